// Round 9
// baseline (142.981 us; speedup 1.0000x reference)
//
#include <hip/hip_runtime.h>
#include <stdint.h>

typedef unsigned short u16;
typedef __attribute__((ext_vector_type(8))) short short8;
typedef __attribute__((ext_vector_type(4))) float f32x4;

__device__ __forceinline__ u16 f2bf(float f) {
  union { float f; unsigned int u; } c; c.f = f;
  return (u16)((c.u + 0x7FFFu + ((c.u >> 16) & 1u)) >> 16);
}

__device__ __forceinline__ float bf2f(u16 v) {
  union { unsigned int u; float f; } c; c.u = ((unsigned int)v) << 16;
  return c.f;
}

__device__ __forceinline__ f32x4 mfma16(short8 a, short8 b, f32x4 c) {
  return __builtin_amdgcn_mfma_f32_16x16x32_bf16(a, b, c, 0, 0, 0);
}

__device__ __forceinline__ void gl_lds16(const u16* g, u16* l) {
  __builtin_amdgcn_global_load_lds((const __attribute__((address_space(1))) void*)g,
                                   (__attribute__((address_space(3))) void*)l, 16, 0, 0);
}

// ---------------- fused cast f32 -> bf16 ----------------
__global__ __launch_bounds__(256) void cast_all(
    const float* __restrict__ x, const float* __restrict__ wq, const float* __restrict__ wk,
    const float* __restrict__ wv, const float* __restrict__ wo,
    u16* __restrict__ xb, u16* __restrict__ wqb, u16* __restrict__ wkb,
    u16* __restrict__ wvb, u16* __restrict__ wob) {
  int b = blockIdx.x;
  const float* src; u16* dst; int i;
  if (b < 4096)      { src = x;  dst = xb;  i = b * 256 + threadIdx.x; }
  else if (b < 5120) { src = wq; dst = wqb; i = (b - 4096) * 256 + threadIdx.x; }
  else if (b < 6144) { src = wk; dst = wkb; i = (b - 5120) * 256 + threadIdx.x; }
  else if (b < 7168) { src = wv; dst = wvb; i = (b - 6144) * 256 + threadIdx.x; }
  else               { src = wo; dst = wob; i = (b - 7168) * 256 + threadIdx.x; }
  float4 v = ((const float4*)src)[i];
  ushort4 o;
  o.x = f2bf(v.x); o.y = f2bf(v.y); o.z = f2bf(v.z); o.w = f2bf(v.w);
  ((ushort4*)dst)[i] = o;
}

// ---------------- fused QKV projection GEMM (XCD-pinned A-panels) -----------
// Logical tile (z, mblk, nblk) mapped so id%8 == mblk%8: XCD x keeps A-panels
// {x, x+8, x+16, x+24} L2-resident; W panels get 4-way reuse.
// z==0 -> Q scaled by (1/8)*log2(e) ; z==1 -> K ; z==2 -> V^T (B,H,D,T)
__global__ __launch_bounds__(256) void qkv_gemm(
    const u16* __restrict__ xb, const u16* __restrict__ wqb, const u16* __restrict__ wkb,
    const u16* __restrict__ wvb, const float* __restrict__ bq, const float* __restrict__ bk,
    const float* __restrict__ bv, u16* __restrict__ Qb, u16* __restrict__ Kb,
    u16* __restrict__ VTb) {
  __shared__ __align__(16) u16 As[128 * 32];
  __shared__ __align__(16) u16 Bs[128 * 32];
  const int id = blockIdx.x;
  const int s = id >> 3;
  const int mblk = (id & 7) + ((s & 3) << 3);
  const int z = (s >> 2) % 3;
  const int nblk = s / 12;
  const u16* __restrict__ W = (z == 0) ? wqb : (z == 1) ? wkb : wvb;
  const float* __restrict__ bias = (z == 0) ? bq : (z == 1) ? bk : bv;
  const int m0 = mblk * 128, n0 = nblk * 128;
  const int tid = threadIdx.x, lane = tid & 63, wave = tid >> 6;
  const int wr = (wave >> 1) * 64, wc = (wave & 1) * 64;
  const int fr = lane & 15, fg = lane >> 4;
  const int lrow = lane >> 2, lcol = (lane & 3) * 8;

  const u16* ga = xb + (size_t)(m0 + wave * 16 + lrow) * 1024 + lcol;
  const u16* gb = W  + (size_t)(n0 + wave * 16 + lrow) * 1024 + lcol;
  u16* la = As + wave * 512;
  u16* lb = Bs + wave * 512;

  f32x4 acc[4][4] = {};

  for (int k0 = 0; k0 < 1024; k0 += 32) {
    gl_lds16(ga + k0, la);
    gl_lds16(ga + 64 * 1024 + k0, la + 2048);
    gl_lds16(gb + k0, lb);
    gl_lds16(gb + 64 * 1024 + k0, lb + 2048);
    __syncthreads();
    short8 a[4], b[4];
#pragma unroll
    for (int i = 0; i < 4; ++i) a[i] = *(const short8*)(As + (wr + i * 16 + fr) * 32 + fg * 8);
#pragma unroll
    for (int i = 0; i < 4; ++i) b[i] = *(const short8*)(Bs + (wc + i * 16 + fr) * 32 + fg * 8);
#pragma unroll
    for (int i = 0; i < 4; ++i)
#pragma unroll
      for (int j = 0; j < 4; ++j) acc[i][j] = mfma16(a[i], b[j], acc[i][j]);
    __syncthreads();
  }

  const float qsc = (z == 0) ? (0.125f * 1.44269504088896f) : 1.0f;
#pragma unroll
  for (int j = 0; j < 4; ++j) {
    const int col = n0 + wc + j * 16 + fr;
    const float bcol = bias[col];
    const int h = col >> 6, d = col & 63;
#pragma unroll
    for (int i = 0; i < 4; ++i) {
#pragma unroll
      for (int r = 0; r < 4; ++r) {
        const int m = m0 + wr + i * 16 + fg * 4 + r;
        const int bi = m >> 11, t = m & 2047;
        const u16 o = f2bf((acc[i][j][r] + bcol) * qsc);
        const size_t bse = (size_t)(bi * 16 + h) << 17;
        if (z == 0)      Qb[bse + (size_t)t * 64 + d] = o;
        else if (z == 1) Kb[bse + (size_t)t * 64 + d] = o;
        else             VTb[bse + (size_t)d * 2048 + t] = o;
      }
    }
  }
}

// ---------------- flash causal attention (paired 32-row q-tiles) -------------
// grid 1024: bh = id & 31 (head's blocks share an XCD), p = id>>5 in 0..31.
// Block p does q-tiles jj = 63-p then p (32 rows each): every block = exactly
// 33 KV-tile-units -> zero tail at 4 blocks/CU. Wave w takes KV tiles w, w+4...
// Fixed-base softmax (m=0): P = exp2(min(s,80)), per-lane l, no cross-lane ops.
__global__ __launch_bounds__(256, 2) void attn_kernel(
    const u16* __restrict__ Qb, const u16* __restrict__ Kb, const u16* __restrict__ VTb,
    u16* __restrict__ aOb) {
  __shared__ __align__(16) char smem[4 * 32 * 72 * 2];  // Ow [4][32][72] u16, 18.4 KB
  __shared__ float Mll[4][4][32];                       // l partials, 2 KB
  u16* Ow = (u16*)smem;
  uint32_t* Pw = (uint32_t*)smem;  // [4][16][32] u32, 8 KB — disjoint lifetime vs Ow
  const int id = blockIdx.x;
  const int bh = id & 31, p = id >> 5;
  const int tid = threadIdx.x, lane = tid & 63, wave = tid >> 6;
  const int fr = lane & 15, fg = lane >> 4;
  const size_t base = (size_t)bh << 17;
  const int bi = bh >> 4, h = bh & 15;
  const int swz = (fr & 7) << 4;
  char* prow = (char*)&Pw[(wave * 16 + fr) * 32];

#pragma unroll
  for (int pass = 0; pass < 2; ++pass) {
    const int jj = pass ? p : (63 - p);   // 32-row q-tile index
    const int q0 = jj * 32;
    const int nt = (jj >> 1) + 1;         // KV tiles (64 wide) needed

    // Q fragments, 2 row-groups (pre-scaled by 0.125*log2e)
    short8 qf[2][2];
#pragma unroll
    for (int mi = 0; mi < 2; ++mi)
#pragma unroll
      for (int kk = 0; kk < 2; ++kk)
        qf[mi][kk] = *(const short8*)(Qb + base +
                      (size_t)(q0 + mi * 16 + fr) * 64 + kk * 32 + fg * 8);

    f32x4 oacc[2][4] = {};
    float lrun[2] = {0.f, 0.f};

    for (int ti = wave; ti < nt; ti += 4) {
      const int t0 = ti * 64;
      // K fragments direct from global (L2): K[t0+ni*16+fr][kk*32+fg*8..)
      const u16* kp = Kb + base + (size_t)(t0 + fr) * 64 + fg * 8;
      short8 kf[4][2];
#pragma unroll
      for (int ni = 0; ni < 4; ++ni) {
        kf[ni][0] = *(const short8*)(kp + ni * 1024);
        kf[ni][1] = *(const short8*)(kp + ni * 1024 + 32);
      }
      // V fragments: V^T[d=ni*16+fr][t0+kk*32+fg*8..)
      const u16* vp = VTb + base + (size_t)fr * 2048 + t0 + fg * 8;
      short8 vf[4][2];
#pragma unroll
      for (int ni = 0; ni < 4; ++ni) {
        vf[ni][0] = *(const short8*)(vp + (size_t)ni * 32768);
        vf[ni][1] = *(const short8*)(vp + (size_t)ni * 32768 + 32);
      }

#pragma unroll
      for (int mi = 0; mi < 2; ++mi) {
        // S^T = K Q^T : lane fr = q-row (group mi), s[ni][r] = S[fr][ni*16+fg*4+r]
        f32x4 s[4] = {};
        __builtin_amdgcn_s_setprio(1);
#pragma unroll
        for (int ni = 0; ni < 4; ++ni) {
          s[ni] = mfma16(kf[ni][0], qf[mi][0], s[ni]);
          s[ni] = mfma16(kf[ni][1], qf[mi][1], s[ni]);
        }
        __builtin_amdgcn_s_setprio(0);

        if (ti == nt - 1) {  // last tile overlaps the diagonal
          const int rlim = (mi * 16 + fr) + (q0 - t0);  // mask t-local > rlim
#pragma unroll
          for (int ni = 0; ni < 4; ++ni)
#pragma unroll
            for (int r = 0; r < 4; ++r)
              if (ni * 16 + fg * 4 + r > rlim) s[ni][r] = -1e30f;
        }

        // fixed-base softmax: P = exp2(min(s,80)); per-lane l partial
        float rs = 0.f;
#pragma unroll
        for (int ni = 0; ni < 4; ++ni)
#pragma unroll
          for (int r = 0; r < 4; ++r) {
            const float pv = exp2f(fminf(s[ni][r], 80.f));
            s[ni][r] = pv;
            rs += pv;
          }
        lrun[mi] += rs;

        // pack P -> bf16, exchange via wave-private swizzled LDS rows
#pragma unroll
        for (int ni = 0; ni < 4; ++ni) {
          float a0 = s[ni][0], a1 = s[ni][1], a2 = s[ni][2], a3 = s[ni][3];
          uint32_t w0, w1;
          asm("v_cvt_pk_bf16_f32 %0, %1, %2" : "=v"(w0) : "v"(a0), "v"(a1));
          asm("v_cvt_pk_bf16_f32 %0, %1, %2" : "=v"(w1) : "v"(a2), "v"(a3));
          *(uint2*)(prow + ((ni * 32 + fg * 8) ^ swz)) = make_uint2(w0, w1);
        }
        short8 pf[2];
#pragma unroll
        for (int kk = 0; kk < 2; ++kk)
          pf[kk] = *(const short8*)(prow + ((kk * 64 + fg * 16) ^ swz));

        // O += P V (no rescale — fixed base)
        __builtin_amdgcn_s_setprio(1);
#pragma unroll
        for (int ni = 0; ni < 4; ++ni) {
          oacc[mi][ni] = mfma16(pf[0], vf[ni][0], oacc[mi][ni]);
          oacc[mi][ni] = mfma16(pf[1], vf[ni][1], oacc[mi][ni]);
        }
        __builtin_amdgcn_s_setprio(0);
      }
    }

    __syncthreads();  // Pw dead; Ow takes over the aliased space
#pragma unroll
    for (int mi = 0; mi < 2; ++mi) Mll[wave][fg][mi * 16 + fr] = lrun[mi];
#pragma unroll
    for (int mi = 0; mi < 2; ++mi)
#pragma unroll
      for (int ni = 0; ni < 4; ++ni)
#pragma unroll
        for (int r = 0; r < 4; ++r)
          Ow[(wave * 32 + mi * 16 + fg * 4 + r) * 72 + ni * 16 + fr] = f2bf(oacc[mi][ni][r]);
    __syncthreads();

    // combine: thread -> q-row rq = tid>>3 (0..31), d-chunk c0 = (tid&7)*8
    const int rq = tid >> 3, c0 = (tid & 7) * 8;
    float lt = 0.f;
#pragma unroll
    for (int w = 0; w < 4; ++w)
#pragma unroll
      for (int g = 0; g < 4; ++g) lt += Mll[w][g][rq];
    const float inv = __builtin_amdgcn_rcpf(lt);
    float o[8] = {};
#pragma unroll
    for (int w = 0; w < 4; ++w) {
      short8 a = *(const short8*)&Ow[(w * 32 + rq) * 72 + c0];
#pragma unroll
      for (int i = 0; i < 8; ++i) o[i] += bf2f((u16)a[i]);
    }
    short8 r0;
#pragma unroll
    for (int i = 0; i < 8; ++i) r0[i] = (short)f2bf(o[i] * inv);
    *(short8*)(aOb + ((size_t)bi * 2048 + q0 + rq) * 1024 + h * 64 + c0) = r0;
    __syncthreads();  // protect Ow before next pass reuses it as Pw
  }
}

// ---------------- output projection GEMM (XCD-pinned A-panels) ---------------
__global__ __launch_bounds__(256) void out_gemm(
    const u16* __restrict__ Ab, const u16* __restrict__ Wb, const float* __restrict__ bo,
    float* __restrict__ out) {
  __shared__ __align__(16) u16 As[128 * 32];
  __shared__ __align__(16) u16 Bs[128 * 32];
  const int id = blockIdx.x;
  const int s = id >> 3;
  const int m0 = ((id & 7) + ((s & 3) << 3)) * 128;
  const int n0 = (s >> 2) * 128;
  const int tid = threadIdx.x, lane = tid & 63, wave = tid >> 6;
  const int wr = (wave >> 1) * 64, wc = (wave & 1) * 64;
  const int fr = lane & 15, fg = lane >> 4;
  const int lrow = lane >> 2, lcol = (lane & 3) * 8;

  const u16* ga = Ab + (size_t)(m0 + wave * 16 + lrow) * 1024 + lcol;
  const u16* gb = Wb + (size_t)(n0 + wave * 16 + lrow) * 1024 + lcol;
  u16* la = As + wave * 512;
  u16* lb = Bs + wave * 512;

  f32x4 acc[4][4] = {};

  for (int k0 = 0; k0 < 1024; k0 += 32) {
    gl_lds16(ga + k0, la);
    gl_lds16(ga + 64 * 1024 + k0, la + 2048);
    gl_lds16(gb + k0, lb);
    gl_lds16(gb + 64 * 1024 + k0, lb + 2048);
    __syncthreads();
    short8 a[4], b[4];
#pragma unroll
    for (int i = 0; i < 4; ++i) a[i] = *(const short8*)(As + (wr + i * 16 + fr) * 32 + fg * 8);
#pragma unroll
    for (int i = 0; i < 4; ++i) b[i] = *(const short8*)(Bs + (wc + i * 16 + fr) * 32 + fg * 8);
#pragma unroll
    for (int i = 0; i < 4; ++i)
#pragma unroll
      for (int j = 0; j < 4; ++j) acc[i][j] = mfma16(a[i], b[j], acc[i][j]);
    __syncthreads();
  }

#pragma unroll
  for (int j = 0; j < 4; ++j) {
    const int col = n0 + wc + j * 16 + fr;
    const float bcol = bo[col];
#pragma unroll
    for (int i = 0; i < 4; ++i)
#pragma unroll
      for (int r = 0; r < 4; ++r) {
        const int m = m0 + wr + i * 16 + fg * 4 + r;
        out[(size_t)m * 1024 + col] = acc[i][j][r] + bcol;
      }
  }
}

extern "C" void kernel_launch(void* const* d_in, const int* in_sizes, int n_in,
                              void* d_out, int out_size, void* d_ws, size_t ws_size,
                              hipStream_t stream) {
  (void)in_sizes; (void)n_in; (void)out_size; (void)ws_size;
  const float* x  = (const float*)d_in[0];
  const float* Wq = (const float*)d_in[1];
  const float* bq = (const float*)d_in[2];
  const float* Wk = (const float*)d_in[3];
  const float* bk = (const float*)d_in[4];
  const float* Wv = (const float*)d_in[5];
  const float* bv = (const float*)d_in[6];
  const float* Wo = (const float*)d_in[7];
  const float* bo = (const float*)d_in[8];
  float* out = (float*)d_out;
  char* ws = (char*)d_ws;

  const size_t MB = 1024 * 1024;
  u16* xb  = (u16*)(ws);
  u16* wqb = (u16*)(ws + 8 * MB);
  u16* wkb = (u16*)(ws + 10 * MB);
  u16* wvb = (u16*)(ws + 12 * MB);
  u16* wob = (u16*)(ws + 14 * MB);
  u16* Qb  = (u16*)(ws + 16 * MB);
  u16* Kb  = (u16*)(ws + 24 * MB);
  u16* VTb = (u16*)(ws + 32 * MB);
  u16* aOb = (u16*)(ws + 40 * MB);

  cast_all<<<8192, 256, 0, stream>>>(x, Wq, Wk, Wv, Wo, xb, wqb, wkb, wvb, wob);
  qkv_gemm<<<768, 256, 0, stream>>>(xb, wqb, wkb, wvb, bq, bk, bv, Qb, Kb, VTb);
  attn_kernel<<<1024, 256, 0, stream>>>(Qb, Kb, VTb, aOb);
  out_gemm<<<256, 256, 0, stream>>>(aOb, wob, bo, out);
}

// Round 10
// 136.930 us; speedup vs baseline: 1.0442x; 1.0442x over previous
//
#include <hip/hip_runtime.h>
#include <stdint.h>

typedef unsigned short u16;
typedef __attribute__((ext_vector_type(8))) short short8;
typedef __attribute__((ext_vector_type(4))) float f32x4;

__device__ __forceinline__ u16 f2bf(float f) {
  union { float f; unsigned int u; } c; c.f = f;
  return (u16)((c.u + 0x7FFFu + ((c.u >> 16) & 1u)) >> 16);
}

__device__ __forceinline__ float bf2f(u16 v) {
  union { unsigned int u; float f; } c; c.u = ((unsigned int)v) << 16;
  return c.f;
}

__device__ __forceinline__ f32x4 mfma16(short8 a, short8 b, f32x4 c) {
  return __builtin_amdgcn_mfma_f32_16x16x32_bf16(a, b, c, 0, 0, 0);
}

__device__ __forceinline__ void gl_lds16(const u16* g, u16* l) {
  __builtin_amdgcn_global_load_lds((const __attribute__((address_space(1))) void*)g,
                                   (__attribute__((address_space(3))) void*)l, 16, 0, 0);
}

// ---------------- fused cast f32 -> bf16 ----------------
__global__ __launch_bounds__(256) void cast_all(
    const float* __restrict__ x, const float* __restrict__ wq, const float* __restrict__ wk,
    const float* __restrict__ wv, const float* __restrict__ wo,
    u16* __restrict__ xb, u16* __restrict__ wqb, u16* __restrict__ wkb,
    u16* __restrict__ wvb, u16* __restrict__ wob) {
  int b = blockIdx.x;
  const float* src; u16* dst; int i;
  if (b < 4096)      { src = x;  dst = xb;  i = b * 256 + threadIdx.x; }
  else if (b < 5120) { src = wq; dst = wqb; i = (b - 4096) * 256 + threadIdx.x; }
  else if (b < 6144) { src = wk; dst = wkb; i = (b - 5120) * 256 + threadIdx.x; }
  else if (b < 7168) { src = wv; dst = wvb; i = (b - 6144) * 256 + threadIdx.x; }
  else               { src = wo; dst = wob; i = (b - 7168) * 256 + threadIdx.x; }
  float4 v = ((const float4*)src)[i];
  ushort4 o;
  o.x = f2bf(v.x); o.y = f2bf(v.y); o.z = f2bf(v.z); o.w = f2bf(v.w);
  ((ushort4*)dst)[i] = o;
}

// ---------------- fused QKV projection GEMM (XCD-pinned A-panels) -----------
__global__ __launch_bounds__(256) void qkv_gemm(
    const u16* __restrict__ xb, const u16* __restrict__ wqb, const u16* __restrict__ wkb,
    const u16* __restrict__ wvb, const float* __restrict__ bq, const float* __restrict__ bk,
    const float* __restrict__ bv, u16* __restrict__ Qb, u16* __restrict__ Kb,
    u16* __restrict__ VTb) {
  __shared__ __align__(16) u16 As[128 * 32];
  __shared__ __align__(16) u16 Bs[128 * 32];
  const int id = blockIdx.x;
  const int s = id >> 3;
  const int mblk = (id & 7) + ((s & 3) << 3);
  const int z = (s >> 2) % 3;
  const int nblk = s / 12;
  const u16* __restrict__ W = (z == 0) ? wqb : (z == 1) ? wkb : wvb;
  const float* __restrict__ bias = (z == 0) ? bq : (z == 1) ? bk : bv;
  const int m0 = mblk * 128, n0 = nblk * 128;
  const int tid = threadIdx.x, lane = tid & 63, wave = tid >> 6;
  const int wr = (wave >> 1) * 64, wc = (wave & 1) * 64;
  const int fr = lane & 15, fg = lane >> 4;
  const int lrow = lane >> 2, lcol = (lane & 3) * 8;

  const u16* ga = xb + (size_t)(m0 + wave * 16 + lrow) * 1024 + lcol;
  const u16* gb = W  + (size_t)(n0 + wave * 16 + lrow) * 1024 + lcol;
  u16* la = As + wave * 512;
  u16* lb = Bs + wave * 512;

  f32x4 acc[4][4] = {};

  for (int k0 = 0; k0 < 1024; k0 += 32) {
    gl_lds16(ga + k0, la);
    gl_lds16(ga + 64 * 1024 + k0, la + 2048);
    gl_lds16(gb + k0, lb);
    gl_lds16(gb + 64 * 1024 + k0, lb + 2048);
    __syncthreads();
    short8 a[4], b[4];
#pragma unroll
    for (int i = 0; i < 4; ++i) a[i] = *(const short8*)(As + (wr + i * 16 + fr) * 32 + fg * 8);
#pragma unroll
    for (int i = 0; i < 4; ++i) b[i] = *(const short8*)(Bs + (wc + i * 16 + fr) * 32 + fg * 8);
#pragma unroll
    for (int i = 0; i < 4; ++i)
#pragma unroll
      for (int j = 0; j < 4; ++j) acc[i][j] = mfma16(a[i], b[j], acc[i][j]);
    __syncthreads();
  }

  const float qsc = (z == 0) ? (0.125f * 1.44269504088896f) : 1.0f;
#pragma unroll
  for (int j = 0; j < 4; ++j) {
    const int col = n0 + wc + j * 16 + fr;
    const float bcol = bias[col];
    const int h = col >> 6, d = col & 63;
#pragma unroll
    for (int i = 0; i < 4; ++i) {
#pragma unroll
      for (int r = 0; r < 4; ++r) {
        const int m = m0 + wr + i * 16 + fg * 4 + r;
        const int bi = m >> 11, t = m & 2047;
        const u16 o = f2bf((acc[i][j][r] + bcol) * qsc);
        const size_t bse = (size_t)(bi * 16 + h) << 17;
        if (z == 0)      Qb[bse + (size_t)t * 64 + d] = o;
        else if (z == 1) Kb[bse + (size_t)t * 64 + d] = o;
        else             VTb[bse + (size_t)d * 2048 + t] = o;
      }
    }
  }
}

// ---------------- flash causal attention (split-KV, fixed-base softmax) ------
// grid 2560: bh = id & 31 (head pinned to one XCD), r = id>>5 in 0..79 maps to
// (j, chunk): j<8 -> 1 chunk, j<16 -> 2, j<24 -> 3, else 4 (8 KV tiles/chunk).
// Block = 64-row q-tile j, KV tiles [8c, min(8c+7, j)]; wave w takes 8c+w, +4.
// Fixed-base softmax (m=0): partials combine by plain sum. j<8 writes output
// directly; others write bf16 O-partial + l for the merge kernel.
__global__ __launch_bounds__(256, 2) void attn_kernel(
    const u16* __restrict__ Qb, const u16* __restrict__ Kb, const u16* __restrict__ VTb,
    u16* __restrict__ Opart, float* __restrict__ Lpart, u16* __restrict__ aOb) {
  __shared__ __align__(16) char smem[4 * 64 * 72 * 2];  // Ow [4][64][72] u16, 36.9 KB
  __shared__ float Mll[4][4][64];                       // l partials, 4 KB
  u16* Ow = (u16*)smem;
  uint32_t* Pw = (uint32_t*)smem;  // [4][16][32] u32, 8 KB — disjoint lifetime vs Ow
  const int id = blockIdx.x;
  const int bh = id & 31, r = id >> 5;
  int j, c;
  if (r < 8)       { j = r;                  c = 0; }
  else if (r < 24) { j = 8 + ((r - 8) >> 1); c = (r - 8) & 1; }
  else if (r < 48) { j = 16 + (r - 24) / 3;  c = (r - 24) % 3; }
  else             { j = 24 + ((r - 48) >> 2); c = (r - 48) & 3; }
  const int tid = threadIdx.x, lane = tid & 63, wave = tid >> 6;
  const int fr = lane & 15, fg = lane >> 4;
  const size_t base = (size_t)bh << 17;
  const int bi = bh >> 4, h = bh & 15;
  const int swz = (fr & 7) << 4;
  const int q0 = j * 64;
  char* prow = (char*)&Pw[(wave * 16 + fr) * 32];

  // Q fragments for all 4 row-groups (pre-scaled by 0.125*log2e)
  short8 qf[4][2];
#pragma unroll
  for (int mi = 0; mi < 4; ++mi)
#pragma unroll
    for (int kk = 0; kk < 2; ++kk)
      qf[mi][kk] = *(const short8*)(Qb + base +
                    (size_t)(q0 + mi * 16 + fr) * 64 + kk * 32 + fg * 8);

  f32x4 oacc[4][4] = {};
  float lrun[4] = {0.f, 0.f, 0.f, 0.f};

  const int thi = min(c * 8 + 7, j);
  for (int ti = c * 8 + wave; ti <= thi; ti += 4) {
    const int t0 = ti * 64;
    const u16* kp = Kb + base + (size_t)(t0 + fr) * 64 + fg * 8;
    short8 kf[4][2];
#pragma unroll
    for (int ni = 0; ni < 4; ++ni) {
      kf[ni][0] = *(const short8*)(kp + ni * 1024);
      kf[ni][1] = *(const short8*)(kp + ni * 1024 + 32);
    }
    const u16* vp = VTb + base + (size_t)fr * 2048 + t0 + fg * 8;
    short8 vf[4][2];
#pragma unroll
    for (int ni = 0; ni < 4; ++ni) {
      vf[ni][0] = *(const short8*)(vp + (size_t)ni * 32768);
      vf[ni][1] = *(const short8*)(vp + (size_t)ni * 32768 + 32);
    }

#pragma unroll
    for (int mi = 0; mi < 4; ++mi) {
      // S^T = K Q^T : lane fr = q-row (group mi), s[ni][r] = S[fr][ni*16+fg*4+r]
      f32x4 s[4] = {};
      __builtin_amdgcn_s_setprio(1);
#pragma unroll
      for (int ni = 0; ni < 4; ++ni) {
        s[ni] = mfma16(kf[ni][0], qf[mi][0], s[ni]);
        s[ni] = mfma16(kf[ni][1], qf[mi][1], s[ni]);
      }
      __builtin_amdgcn_s_setprio(0);

      if (ti == j) {  // diagonal tile: mask t_local > q_local
        const int rloc = mi * 16 + fr;
#pragma unroll
        for (int ni = 0; ni < 4; ++ni)
#pragma unroll
          for (int rr = 0; rr < 4; ++rr)
            if (ni * 16 + fg * 4 + rr > rloc) s[ni][rr] = -1e30f;
      }

      // fixed-base softmax: P = exp2(min(s,80)); per-lane l partial; no shfl
      float rs = 0.f;
#pragma unroll
      for (int ni = 0; ni < 4; ++ni)
#pragma unroll
        for (int rr = 0; rr < 4; ++rr) {
          const float pv = exp2f(fminf(s[ni][rr], 80.f));
          s[ni][rr] = pv;
          rs += pv;
        }
      lrun[mi] += rs;

      // pack P -> bf16, exchange via wave-private swizzled LDS rows
#pragma unroll
      for (int ni = 0; ni < 4; ++ni) {
        float a0 = s[ni][0], a1 = s[ni][1], a2 = s[ni][2], a3 = s[ni][3];
        uint32_t w0, w1;
        asm("v_cvt_pk_bf16_f32 %0, %1, %2" : "=v"(w0) : "v"(a0), "v"(a1));
        asm("v_cvt_pk_bf16_f32 %0, %1, %2" : "=v"(w1) : "v"(a2), "v"(a3));
        *(uint2*)(prow + ((ni * 32 + fg * 8) ^ swz)) = make_uint2(w0, w1);
      }
      short8 pf[2];
#pragma unroll
      for (int kk = 0; kk < 2; ++kk)
        pf[kk] = *(const short8*)(prow + ((kk * 64 + fg * 16) ^ swz));

      // O += P V (no rescale — fixed base)
      __builtin_amdgcn_s_setprio(1);
#pragma unroll
      for (int ni = 0; ni < 4; ++ni) {
        oacc[mi][ni] = mfma16(pf[0], vf[ni][0], oacc[mi][ni]);
        oacc[mi][ni] = mfma16(pf[1], vf[ni][1], oacc[mi][ni]);
      }
      __builtin_amdgcn_s_setprio(0);
    }
  }

  __syncthreads();  // Pw dead; Ow takes over aliased space
#pragma unroll
  for (int mi = 0; mi < 4; ++mi) Mll[wave][fg][mi * 16 + fr] = lrun[mi];
#pragma unroll
  for (int mi = 0; mi < 4; ++mi)
#pragma unroll
    for (int ni = 0; ni < 4; ++ni)
#pragma unroll
      for (int rr = 0; rr < 4; ++rr)
        Ow[(wave * 64 + mi * 16 + fg * 4 + rr) * 72 + ni * 16 + fr] = f2bf(oacc[mi][ni][rr]);
  __syncthreads();

  // combine the 4 waves: thread -> q-row rq = tid>>2, d-chunk c0 = (tid&3)*16
  const int rq = tid >> 2, c0 = (tid & 3) * 16;
  float lt = 0.f;
#pragma unroll
  for (int w = 0; w < 4; ++w)
#pragma unroll
    for (int g = 0; g < 4; ++g) lt += Mll[w][g][rq];
  float o[16] = {};
#pragma unroll
  for (int w = 0; w < 4; ++w) {
    const u16* orow = &Ow[(w * 64 + rq) * 72 + c0];
    short8 a = *(const short8*)orow;
    short8 b = *(const short8*)(orow + 8);
#pragma unroll
    for (int i = 0; i < 8; ++i) {
      o[i]     += bf2f((u16)a[i]);
      o[8 + i] += bf2f((u16)b[i]);
    }
  }
  if (j < 8) {  // single chunk: finalize directly
    const float inv = __builtin_amdgcn_rcpf(lt);
    short8 r0, r1;
#pragma unroll
    for (int i = 0; i < 8; ++i) {
      r0[i] = (short)f2bf(o[i] * inv);
      r1[i] = (short)f2bf(o[8 + i] * inv);
    }
    u16* op = aOb + ((size_t)bi * 2048 + q0 + rq) * 1024 + h * 64 + c0;
    *(short8*)op = r0;
    *(short8*)(op + 8) = r1;
  } else {      // write bf16 partial + l for merge
    short8 r0, r1;
#pragma unroll
    for (int i = 0; i < 8; ++i) {
      r0[i] = (short)f2bf(o[i]);
      r1[i] = (short)f2bf(o[8 + i]);
    }
    u16* op = Opart + (size_t)id * 4096 + rq * 64 + c0;
    *(short8*)op = r0;
    *(short8*)(op + 8) = r1;
    if ((tid & 3) == 0) Lpart[id * 64 + rq] = lt;
  }
}

// ---------------- partial merge (plain sum — fixed base) ---------------------
// grid 768: bh = id & 31, j = 8 + (id>>5) in 8..31. Sums nc=(j>>3)+1 partials.
__global__ __launch_bounds__(256) void attn_merge(
    const u16* __restrict__ Opart, const float* __restrict__ Lpart,
    u16* __restrict__ aOb) {
  const int id = blockIdx.x;
  const int bh = id & 31, j = 8 + (id >> 5);
  const int nc = (j >> 3) + 1;
  const int tid = threadIdx.x;
  const int rq = tid >> 2, c0 = (tid & 3) * 16;
  const int bi = bh >> 4, h = bh & 15;
  float o[16] = {};
  float lt = 0.f;
  for (int cc = 0; cc < nc; ++cc) {
    const int rr = (j < 16) ? 8 + ((j - 8) << 1) + cc
                 : (j < 24) ? 24 + 3 * (j - 16) + cc
                            : 48 + ((j - 24) << 2) + cc;
    const int slot = (rr << 5) | bh;
    lt += Lpart[slot * 64 + rq];
    const u16* op = Opart + (size_t)slot * 4096 + rq * 64 + c0;
    short8 a = *(const short8*)op;
    short8 b = *(const short8*)(op + 8);
#pragma unroll
    for (int i = 0; i < 8; ++i) {
      o[i]     += bf2f((u16)a[i]);
      o[8 + i] += bf2f((u16)b[i]);
    }
  }
  const float inv = __builtin_amdgcn_rcpf(lt);
  short8 r0, r1;
#pragma unroll
  for (int i = 0; i < 8; ++i) {
    r0[i] = (short)f2bf(o[i] * inv);
    r1[i] = (short)f2bf(o[8 + i] * inv);
  }
  u16* op = aOb + ((size_t)bi * 2048 + j * 64 + rq) * 1024 + h * 64 + c0;
  *(short8*)op = r0;
  *(short8*)(op + 8) = r1;
}

// ---------------- output projection GEMM (XCD-pinned A-panels) ---------------
__global__ __launch_bounds__(256) void out_gemm(
    const u16* __restrict__ Ab, const u16* __restrict__ Wb, const float* __restrict__ bo,
    float* __restrict__ out) {
  __shared__ __align__(16) u16 As[128 * 32];
  __shared__ __align__(16) u16 Bs[128 * 32];
  const int id = blockIdx.x;
  const int s = id >> 3;
  const int m0 = ((id & 7) + ((s & 3) << 3)) * 128;
  const int n0 = (s >> 2) * 128;
  const int tid = threadIdx.x, lane = tid & 63, wave = tid >> 6;
  const int wr = (wave >> 1) * 64, wc = (wave & 1) * 64;
  const int fr = lane & 15, fg = lane >> 4;
  const int lrow = lane >> 2, lcol = (lane & 3) * 8;

  const u16* ga = Ab + (size_t)(m0 + wave * 16 + lrow) * 1024 + lcol;
  const u16* gb = Wb + (size_t)(n0 + wave * 16 + lrow) * 1024 + lcol;
  u16* la = As + wave * 512;
  u16* lb = Bs + wave * 512;

  f32x4 acc[4][4] = {};

  for (int k0 = 0; k0 < 1024; k0 += 32) {
    gl_lds16(ga + k0, la);
    gl_lds16(ga + 64 * 1024 + k0, la + 2048);
    gl_lds16(gb + k0, lb);
    gl_lds16(gb + 64 * 1024 + k0, lb + 2048);
    __syncthreads();
    short8 a[4], b[4];
#pragma unroll
    for (int i = 0; i < 4; ++i) a[i] = *(const short8*)(As + (wr + i * 16 + fr) * 32 + fg * 8);
#pragma unroll
    for (int i = 0; i < 4; ++i) b[i] = *(const short8*)(Bs + (wc + i * 16 + fr) * 32 + fg * 8);
#pragma unroll
    for (int i = 0; i < 4; ++i)
#pragma unroll
      for (int j = 0; j < 4; ++j) acc[i][j] = mfma16(a[i], b[j], acc[i][j]);
    __syncthreads();
  }

#pragma unroll
  for (int j = 0; j < 4; ++j) {
    const int col = n0 + wc + j * 16 + fr;
    const float bcol = bo[col];
#pragma unroll
    for (int i = 0; i < 4; ++i)
#pragma unroll
      for (int r = 0; r < 4; ++r) {
        const int m = m0 + wr + i * 16 + fg * 4 + r;
        out[(size_t)m * 1024 + col] = acc[i][j][r] + bcol;
      }
  }
}

extern "C" void kernel_launch(void* const* d_in, const int* in_sizes, int n_in,
                              void* d_out, int out_size, void* d_ws, size_t ws_size,
                              hipStream_t stream) {
  (void)in_sizes; (void)n_in; (void)out_size; (void)ws_size;
  const float* x  = (const float*)d_in[0];
  const float* Wq = (const float*)d_in[1];
  const float* bq = (const float*)d_in[2];
  const float* Wk = (const float*)d_in[3];
  const float* bk = (const float*)d_in[4];
  const float* Wv = (const float*)d_in[5];
  const float* bv = (const float*)d_in[6];
  const float* Wo = (const float*)d_in[7];
  const float* bo = (const float*)d_in[8];
  float* out = (float*)d_out;
  char* ws = (char*)d_ws;

  const size_t MB = 1024 * 1024;
  // Layout (lifetime-aliased):
  //  0- 2: wob                      (live until out_gemm)
  //  2-10: xb  -> aOb              (xb dead after qkv; aOb written by attn/merge)
  // 10-12: wqb -> Lpart            (wqb dead after qkv)
  // 12-14: wkb   14-16: wvb        (dead after qkv)
  // 16-24: Qb   24-32: Kb   32-40: VTb
  // 40-61: Opart (2560 slots x 8 KB)
  u16*   wob   = (u16*)(ws);
  u16*   xb    = (u16*)(ws + 2 * MB);
  u16*   aOb   = (u16*)(ws + 2 * MB);
  u16*   wqb   = (u16*)(ws + 10 * MB);
  float* Lpart = (float*)(ws + 10 * MB);
  u16*   wkb   = (u16*)(ws + 12 * MB);
  u16*   wvb   = (u16*)(ws + 14 * MB);
  u16*   Qb    = (u16*)(ws + 16 * MB);
  u16*   Kb    = (u16*)(ws + 24 * MB);
  u16*   VTb   = (u16*)(ws + 32 * MB);
  u16*   Opart = (u16*)(ws + 40 * MB);

  cast_all<<<8192, 256, 0, stream>>>(x, Wq, Wk, Wv, Wo, xb, wqb, wkb, wvb, wob);
  qkv_gemm<<<768, 256, 0, stream>>>(xb, wqb, wkb, wvb, bq, bk, bv, Qb, Kb, VTb);
  attn_kernel<<<2560, 256, 0, stream>>>(Qb, Kb, VTb, Opart, Lpart, aOb);
  attn_merge<<<768, 256, 0, stream>>>(Opart, Lpart, aOb);
  out_gemm<<<256, 256, 0, stream>>>(aOb, wob, bo, out);
}

// Round 11
// 117.333 us; speedup vs baseline: 1.2186x; 1.1670x over previous
//
#include <hip/hip_runtime.h>
#include <stdint.h>

typedef unsigned short u16;
typedef __attribute__((ext_vector_type(8))) short short8;
typedef __attribute__((ext_vector_type(4))) float f32x4;
typedef __attribute__((ext_vector_type(16))) float f32x16;

__device__ __forceinline__ u16 f2bf(float f) {
  union { float f; unsigned int u; } c; c.f = f;
  return (u16)((c.u + 0x7FFFu + ((c.u >> 16) & 1u)) >> 16);
}

__device__ __forceinline__ float bf2f(u16 v) {
  union { unsigned int u; float f; } c; c.u = ((unsigned int)v) << 16;
  return c.f;
}

__device__ __forceinline__ f32x4 mfma16(short8 a, short8 b, f32x4 c) {
  return __builtin_amdgcn_mfma_f32_16x16x32_bf16(a, b, c, 0, 0, 0);
}

__device__ __forceinline__ f32x16 mfma32(short8 a, short8 b, f32x16 c) {
  return __builtin_amdgcn_mfma_f32_32x32x16_bf16(a, b, c, 0, 0, 0);
}

__device__ __forceinline__ void gl_lds16(const u16* g, u16* l) {
  __builtin_amdgcn_global_load_lds((const __attribute__((address_space(1))) void*)g,
                                   (__attribute__((address_space(3))) void*)l, 16, 0, 0);
}

// ---------------- fused cast f32 -> bf16 ----------------
__global__ __launch_bounds__(256) void cast_all(
    const float* __restrict__ x, const float* __restrict__ wq, const float* __restrict__ wk,
    const float* __restrict__ wv, const float* __restrict__ wo,
    u16* __restrict__ xb, u16* __restrict__ wqb, u16* __restrict__ wkb,
    u16* __restrict__ wvb, u16* __restrict__ wob) {
  int b = blockIdx.x;
  const float* src; u16* dst; int i;
  if (b < 4096)      { src = x;  dst = xb;  i = b * 256 + threadIdx.x; }
  else if (b < 5120) { src = wq; dst = wqb; i = (b - 4096) * 256 + threadIdx.x; }
  else if (b < 6144) { src = wk; dst = wkb; i = (b - 5120) * 256 + threadIdx.x; }
  else if (b < 7168) { src = wv; dst = wvb; i = (b - 6144) * 256 + threadIdx.x; }
  else               { src = wo; dst = wob; i = (b - 7168) * 256 + threadIdx.x; }
  float4 v = ((const float4*)src)[i];
  ushort4 o;
  o.x = f2bf(v.x); o.y = f2bf(v.y); o.z = f2bf(v.z); o.w = f2bf(v.w);
  ((ushort4*)dst)[i] = o;
}

// ---------------- fused QKV projection GEMM (XCD-pinned A-panels) -----------
__global__ __launch_bounds__(256) void qkv_gemm(
    const u16* __restrict__ xb, const u16* __restrict__ wqb, const u16* __restrict__ wkb,
    const u16* __restrict__ wvb, const float* __restrict__ bq, const float* __restrict__ bk,
    const float* __restrict__ bv, u16* __restrict__ Qb, u16* __restrict__ Kb,
    u16* __restrict__ VTb) {
  __shared__ __align__(16) u16 As[128 * 32];
  __shared__ __align__(16) u16 Bs[128 * 32];
  const int id = blockIdx.x;
  const int s = id >> 3;
  const int mblk = (id & 7) + ((s & 3) << 3);
  const int z = (s >> 2) % 3;
  const int nblk = s / 12;
  const u16* __restrict__ W = (z == 0) ? wqb : (z == 1) ? wkb : wvb;
  const float* __restrict__ bias = (z == 0) ? bq : (z == 1) ? bk : bv;
  const int m0 = mblk * 128, n0 = nblk * 128;
  const int tid = threadIdx.x, lane = tid & 63, wave = tid >> 6;
  const int wr = (wave >> 1) * 64, wc = (wave & 1) * 64;
  const int fr = lane & 15, fg = lane >> 4;
  const int lrow = lane >> 2, lcol = (lane & 3) * 8;

  const u16* ga = xb + (size_t)(m0 + wave * 16 + lrow) * 1024 + lcol;
  const u16* gb = W  + (size_t)(n0 + wave * 16 + lrow) * 1024 + lcol;
  u16* la = As + wave * 512;
  u16* lb = Bs + wave * 512;

  f32x4 acc[4][4] = {};

  for (int k0 = 0; k0 < 1024; k0 += 32) {
    gl_lds16(ga + k0, la);
    gl_lds16(ga + 64 * 1024 + k0, la + 2048);
    gl_lds16(gb + k0, lb);
    gl_lds16(gb + 64 * 1024 + k0, lb + 2048);
    __syncthreads();
    short8 a[4], b[4];
#pragma unroll
    for (int i = 0; i < 4; ++i) a[i] = *(const short8*)(As + (wr + i * 16 + fr) * 32 + fg * 8);
#pragma unroll
    for (int i = 0; i < 4; ++i) b[i] = *(const short8*)(Bs + (wc + i * 16 + fr) * 32 + fg * 8);
#pragma unroll
    for (int i = 0; i < 4; ++i)
#pragma unroll
      for (int j = 0; j < 4; ++j) acc[i][j] = mfma16(a[i], b[j], acc[i][j]);
    __syncthreads();
  }

  const float qsc = (z == 0) ? (0.125f * 1.44269504088896f) : 1.0f;
#pragma unroll
  for (int j = 0; j < 4; ++j) {
    const int col = n0 + wc + j * 16 + fr;
    const float bcol = bias[col];
    const int h = col >> 6, d = col & 63;
#pragma unroll
    for (int i = 0; i < 4; ++i) {
#pragma unroll
      for (int r = 0; r < 4; ++r) {
        const int m = m0 + wr + i * 16 + fg * 4 + r;
        const int bi = m >> 11, t = m & 2047;
        const u16 o = f2bf((acc[i][j][r] + bcol) * qsc);
        const size_t bse = (size_t)(bi * 16 + h) << 17;
        if (z == 0)      Qb[bse + (size_t)t * 64 + d] = o;
        else if (z == 1) Kb[bse + (size_t)t * 64 + d] = o;
        else             VTb[bse + (size_t)d * 2048 + t] = o;
      }
    }
  }
}

// ---------------- flash causal attention (32x32 MFMA + permlane P-swap) ------
// grid 1024: bh = id & 31 (head pinned to one XCD), j = 31 - (id>>5) (longest
// first). Block = one 64-row q-tile; wave w takes KV tiles w, w+4, ...
// Swapped QK^T in 32x32 shape: lane owns q-row (lane&31); P re-layout to the
// PV A-fragment is done fully in-register via cvt_pk + v_permlane32_swap_b32
// (no LDS in the loop). Fixed-base softmax (m=0), per-lane l, plain-sum merge.
__global__ __launch_bounds__(256, 2) void attn_kernel(
    const u16* __restrict__ Qb, const u16* __restrict__ Kb, const u16* __restrict__ VTb,
    u16* __restrict__ aOb) {
  __shared__ __align__(16) u16 Ow[4 * 64 * 72];  // 36.9 KB partial O
  __shared__ float Mll[4][2][64];                // l partials [wave][hi][row], 2 KB
  const int id = blockIdx.x;
  const int bh = id & 31, j = 31 - (id >> 5);
  const int tid = threadIdx.x, lane = tid & 63, wave = tid >> 6;
  const int l31 = lane & 31, hi = lane >> 5;
  const size_t base = (size_t)bh << 17;
  const int bi = bh >> 4, h = bh & 15;
  const int q0 = j * 64;

  // Q as B-fragments: lane holds Q[q0+mi*32+l31][step*16 + hi*8 .. +8)
  short8 qf[2][4];
  {
    const u16* qp = Qb + base + (size_t)(q0 + l31) * 64 + hi * 8;
#pragma unroll
    for (int mi = 0; mi < 2; ++mi)
#pragma unroll
      for (int st = 0; st < 4; ++st)
        qf[mi][st] = *(const short8*)(qp + mi * 32 * 64 + st * 16);
  }

  f32x16 oacc[2][2] = {};
  float lrun[2] = {0.f, 0.f};

  for (int ti = wave; ti <= j; ti += 4) {
    const int t0 = ti * 64;
    // K as A-fragments: lane holds K[t0+tb*32+l31][st*16 + hi*8 ..)
    const u16* kp = Kb + base + (size_t)(t0 + l31) * 64 + hi * 8;
    short8 kf[2][4];
#pragma unroll
    for (int tb = 0; tb < 2; ++tb)
#pragma unroll
      for (int st = 0; st < 4; ++st)
        kf[tb][st] = *(const short8*)(kp + tb * 32 * 64 + st * 16);
    // V as B-fragments: lane holds V^T[nb*32+l31][t0+tb*32+ks*16+hi*8 ..)
    const u16* vp = VTb + base + (size_t)l31 * 2048 + t0 + hi * 8;
    short8 vf[2][2][2];  // [nb][tb][ks]
#pragma unroll
    for (int nb = 0; nb < 2; ++nb)
#pragma unroll
      for (int tb = 0; tb < 2; ++tb)
#pragma unroll
        for (int ks = 0; ks < 2; ++ks)
          vf[nb][tb][ks] = *(const short8*)(vp + (size_t)nb * 32 * 2048 + tb * 32 + ks * 16);

#pragma unroll
    for (int mi = 0; mi < 2; ++mi) {
#pragma unroll
      for (int tb = 0; tb < 2; ++tb) {
        // S^T block: lane owns q-row q0+mi*32+l31; 16 t-slots (r&3)+8(r>>2)+4hi
        f32x16 s = {};
        __builtin_amdgcn_s_setprio(1);
        s = mfma32(kf[tb][0], qf[mi][0], s);
        s = mfma32(kf[tb][1], qf[mi][1], s);
        s = mfma32(kf[tb][2], qf[mi][2], s);
        s = mfma32(kf[tb][3], qf[mi][3], s);
        __builtin_amdgcn_s_setprio(0);

        if (ti == j) {  // diagonal tile: mask t_local > q_local
          const int qv = mi * 32 + l31;
          const int tbb = tb * 32 + hi * 4;
#pragma unroll
          for (int r = 0; r < 16; ++r) {
            const int tl = tbb + (r & 3) + ((r >> 2) << 3);
            if (tl > qv) s[r] = -1e30f;
          }
        }

        // fixed-base softmax: P = exp2(s); per-lane l partial; no clamp needed
        float rs = 0.f;
#pragma unroll
        for (int r = 0; r < 16; ++r) {
          const float pv = exp2f(s[r]);
          s[r] = pv;
          rs += pv;
        }
        lrun[mi] += rs;

        // pack to bf16 pairs (t-adjacent) and swap halves across lane pairs:
        // after swap(w0,w2): w0 = A-frag word0 (t+0,1), w2 = word2 (t+4,5) etc.
        uint32_t w0, w1, w2, w3, w4, w5, w6, w7;
        asm("v_cvt_pk_bf16_f32 %0, %1, %2" : "=v"(w0) : "v"(s[0]),  "v"(s[1]));
        asm("v_cvt_pk_bf16_f32 %0, %1, %2" : "=v"(w1) : "v"(s[2]),  "v"(s[3]));
        asm("v_cvt_pk_bf16_f32 %0, %1, %2" : "=v"(w2) : "v"(s[4]),  "v"(s[5]));
        asm("v_cvt_pk_bf16_f32 %0, %1, %2" : "=v"(w3) : "v"(s[6]),  "v"(s[7]));
        asm("v_cvt_pk_bf16_f32 %0, %1, %2" : "=v"(w4) : "v"(s[8]),  "v"(s[9]));
        asm("v_cvt_pk_bf16_f32 %0, %1, %2" : "=v"(w5) : "v"(s[10]), "v"(s[11]));
        asm("v_cvt_pk_bf16_f32 %0, %1, %2" : "=v"(w6) : "v"(s[12]), "v"(s[13]));
        asm("v_cvt_pk_bf16_f32 %0, %1, %2" : "=v"(w7) : "v"(s[14]), "v"(s[15]));
        asm("v_permlane32_swap_b32 %0, %1" : "+v"(w0), "+v"(w2));
        asm("v_permlane32_swap_b32 %0, %1" : "+v"(w1), "+v"(w3));
        asm("v_permlane32_swap_b32 %0, %1" : "+v"(w4), "+v"(w6));
        asm("v_permlane32_swap_b32 %0, %1" : "+v"(w5), "+v"(w7));
        short8 pa0, pa1;
        {
          uint32_t* p0 = (uint32_t*)&pa0;
          p0[0] = w0; p0[1] = w1; p0[2] = w2; p0[3] = w3;
          uint32_t* p1 = (uint32_t*)&pa1;
          p1[0] = w4; p1[1] = w5; p1[2] = w6; p1[3] = w7;
        }

        // O += P V (no rescale — fixed base)
        __builtin_amdgcn_s_setprio(1);
        oacc[mi][0] = mfma32(pa0, vf[0][tb][0], oacc[mi][0]);
        oacc[mi][0] = mfma32(pa1, vf[0][tb][1], oacc[mi][0]);
        oacc[mi][1] = mfma32(pa0, vf[1][tb][0], oacc[mi][1]);
        oacc[mi][1] = mfma32(pa1, vf[1][tb][1], oacc[mi][1]);
        __builtin_amdgcn_s_setprio(0);
      }
    }
  }

  // publish partials: l per (wave, hi, row); O per (wave, row, col)
#pragma unroll
  for (int mi = 0; mi < 2; ++mi) Mll[wave][hi][mi * 32 + l31] = lrun[mi];
#pragma unroll
  for (int mi = 0; mi < 2; ++mi)
#pragma unroll
    for (int nb = 0; nb < 2; ++nb)
#pragma unroll
      for (int r = 0; r < 16; ++r) {
        const int q = mi * 32 + (r & 3) + ((r >> 2) << 3) + hi * 4;
        Ow[(wave * 64 + q) * 72 + nb * 32 + l31] = f2bf(oacc[mi][nb][r]);
      }
  __syncthreads();

  // combine the 4 waves: thread -> q-row rq = tid>>2, d-chunk c0 = (tid&3)*16
  const int rq = tid >> 2, c0 = (tid & 3) * 16;
  float lt = 0.f;
#pragma unroll
  for (int w = 0; w < 4; ++w)
#pragma unroll
    for (int g = 0; g < 2; ++g) lt += Mll[w][g][rq];
  const float inv = __builtin_amdgcn_rcpf(lt);
  float o[16] = {};
#pragma unroll
  for (int w = 0; w < 4; ++w) {
    const u16* orow = &Ow[(w * 64 + rq) * 72 + c0];
    short8 a = *(const short8*)orow;
    short8 b = *(const short8*)(orow + 8);
#pragma unroll
    for (int i = 0; i < 8; ++i) {
      o[i]     += bf2f((u16)a[i]);
      o[8 + i] += bf2f((u16)b[i]);
    }
  }
  short8 r0, r1;
#pragma unroll
  for (int i = 0; i < 8; ++i) {
    r0[i] = (short)f2bf(o[i] * inv);
    r1[i] = (short)f2bf(o[8 + i] * inv);
  }
  u16* op = aOb + ((size_t)bi * 2048 + q0 + rq) * 1024 + h * 64 + c0;
  *(short8*)op = r0;
  *(short8*)(op + 8) = r1;
}

// ---------------- output projection GEMM (XCD-pinned A-panels) ---------------
__global__ __launch_bounds__(256) void out_gemm(
    const u16* __restrict__ Ab, const u16* __restrict__ Wb, const float* __restrict__ bo,
    float* __restrict__ out) {
  __shared__ __align__(16) u16 As[128 * 32];
  __shared__ __align__(16) u16 Bs[128 * 32];
  const int id = blockIdx.x;
  const int s = id >> 3;
  const int m0 = ((id & 7) + ((s & 3) << 3)) * 128;
  const int n0 = (s >> 2) * 128;
  const int tid = threadIdx.x, lane = tid & 63, wave = tid >> 6;
  const int wr = (wave >> 1) * 64, wc = (wave & 1) * 64;
  const int fr = lane & 15, fg = lane >> 4;
  const int lrow = lane >> 2, lcol = (lane & 3) * 8;

  const u16* ga = Ab + (size_t)(m0 + wave * 16 + lrow) * 1024 + lcol;
  const u16* gb = Wb + (size_t)(n0 + wave * 16 + lrow) * 1024 + lcol;
  u16* la = As + wave * 512;
  u16* lb = Bs + wave * 512;

  f32x4 acc[4][4] = {};

  for (int k0 = 0; k0 < 1024; k0 += 32) {
    gl_lds16(ga + k0, la);
    gl_lds16(ga + 64 * 1024 + k0, la + 2048);
    gl_lds16(gb + k0, lb);
    gl_lds16(gb + 64 * 1024 + k0, lb + 2048);
    __syncthreads();
    short8 a[4], b[4];
#pragma unroll
    for (int i = 0; i < 4; ++i) a[i] = *(const short8*)(As + (wr + i * 16 + fr) * 32 + fg * 8);
#pragma unroll
    for (int i = 0; i < 4; ++i) b[i] = *(const short8*)(Bs + (wc + i * 16 + fr) * 32 + fg * 8);
#pragma unroll
    for (int i = 0; i < 4; ++i)
#pragma unroll
      for (int j = 0; j < 4; ++j) acc[i][j] = mfma16(a[i], b[j], acc[i][j]);
    __syncthreads();
  }

#pragma unroll
  for (int j = 0; j < 4; ++j) {
    const int col = n0 + wc + j * 16 + fr;
    const float bcol = bo[col];
#pragma unroll
    for (int i = 0; i < 4; ++i)
#pragma unroll
      for (int r = 0; r < 4; ++r) {
        const int m = m0 + wr + i * 16 + fg * 4 + r;
        out[(size_t)m * 1024 + col] = acc[i][j][r] + bcol;
      }
  }
}

extern "C" void kernel_launch(void* const* d_in, const int* in_sizes, int n_in,
                              void* d_out, int out_size, void* d_ws, size_t ws_size,
                              hipStream_t stream) {
  (void)in_sizes; (void)n_in; (void)out_size; (void)ws_size;
  const float* x  = (const float*)d_in[0];
  const float* Wq = (const float*)d_in[1];
  const float* bq = (const float*)d_in[2];
  const float* Wk = (const float*)d_in[3];
  const float* bk = (const float*)d_in[4];
  const float* Wv = (const float*)d_in[5];
  const float* bv = (const float*)d_in[6];
  const float* Wo = (const float*)d_in[7];
  const float* bo = (const float*)d_in[8];
  float* out = (float*)d_out;
  char* ws = (char*)d_ws;

  const size_t MB = 1024 * 1024;
  u16* xb  = (u16*)(ws);
  u16* wqb = (u16*)(ws + 8 * MB);
  u16* wkb = (u16*)(ws + 10 * MB);
  u16* wvb = (u16*)(ws + 12 * MB);
  u16* wob = (u16*)(ws + 14 * MB);
  u16* Qb  = (u16*)(ws + 16 * MB);
  u16* Kb  = (u16*)(ws + 24 * MB);
  u16* VTb = (u16*)(ws + 32 * MB);
  u16* aOb = (u16*)(ws + 40 * MB);

  cast_all<<<8192, 256, 0, stream>>>(x, Wq, Wk, Wv, Wo, xb, wqb, wkb, wvb, wob);
  qkv_gemm<<<768, 256, 0, stream>>>(xb, wqb, wkb, wvb, bq, bk, bv, Qb, Kb, VTb);
  attn_kernel<<<1024, 256, 0, stream>>>(Qb, Kb, VTb, aOb);
  out_gemm<<<256, 256, 0, stream>>>(aOb, wob, bo, out);
}